// Round 6
// baseline (474.335 us; speedup 1.0000x reference)
//
#include <hip/hip_runtime.h>
#include <hip/hip_bf16.h>
#include <stdint.h>

typedef unsigned short u16;
typedef __bf16 bf16x8 __attribute__((ext_vector_type(8)));
typedef float  f32x4  __attribute__((ext_vector_type(4)));
typedef u16    u16x8  __attribute__((ext_vector_type(8)));

__device__ __forceinline__ float bf2f(u16 u) {
    return __uint_as_float(((unsigned)u) << 16);
}
__device__ __forceinline__ u16 f2bf(float f) {   // round-to-nearest-even
    unsigned u = __float_as_uint(f);
    u += 0x7fffu + ((u >> 16) & 1u);
    return (u16)(u >> 16);
}
__device__ __forceinline__ u16x8 maxu16(u16x8 a, u16x8 b) {
    u16x8 r;
    #pragma unroll
    for (int e = 0; e < 8; ++e) r[e] = a[e] > b[e] ? a[e] : b[e];
    return r;
}

#define MFMA16(a, b, c) __builtin_amdgcn_mfma_f32_16x16x32_bf16(a, b, c, 0, 0, 0)

// Static device buffers — no d_ws dependency.
__device__ u16   h2g_buf[262144 * 64];   // h2 [N][64] bf16 (33.5 MB)
__device__ u16   w3b[64 * 64];           // weights pre-converted to bf16
__device__ u16   w4b[128 * 64];
// w5 transposed to MFMA-fragment-contiguous layout:
//   w5t[((c16*6 + s)*64 + lane)*8 + e] = w5[c16*16 + (lane&15)][s*32 + (lane>>4)*8 + e]
// so a wave's B-frag load for (c16, s) is one fully-coalesced 1KB read.
__device__ u16   w5t[64 * 6 * 64 * 8];   // 384 KB, L2-resident per XCD
__device__ float g_buf[1024];            // global column max (>= 0)
__device__ float f1_buf[512];
__device__ float f2_buf[256];

// ---------------------------------------------------------------------------
__global__ void k0_zero() { g_buf[threadIdx.x] = 0.f; }

__global__ void kcvt(const float* __restrict__ w3f, const float* __restrict__ w4f,
                     const float* __restrict__ w5f)
{
    int i = blockIdx.x * 256 + threadIdx.x;     // 816*256 = 208896 = 4096+8192+196608
    if (i < 4096)        w3b[i]        = f2bf(w3f[i]);
    else if (i < 12288)  w4b[i - 4096] = f2bf(w4f[i - 4096]);
    else {
        int o    = i - 12288;                   // 0..196607
        int e    = o & 7;
        int lane = (o >> 3) & 63;
        int sg   = o >> 9;                      // c16*6 + s
        int s    = sg % 6, c16 = sg / 6;
        int q    = lane >> 4, l15 = lane & 15;
        w5t[o] = f2bf(w5f[(c16 * 16 + l15) * 192 + s * 32 + q * 8 + e]);
    }
}

// ---------------------------------------------------------------------------
// k1: mlp1+mlp2 for 64 points/block (f32 in -> bf16). Writes h2g_buf.
// ---------------------------------------------------------------------------
__global__ __launch_bounds__(256) void k1_mlp(
    const float* __restrict__ xf, const float* __restrict__ w1f,
    const float* __restrict__ w2f)
{
    __shared__ __align__(16) u16 sw1[64 * 4];
    __shared__ __align__(16) u16 sx [64 * 4];
    __shared__ __align__(16) u16 sw2[64 * 72];
    __shared__ __align__(16) u16 shA[64 * 72];
    __shared__ __align__(16) u16 sh2[64 * 72];

    const int tid = threadIdx.x;
    const int p0  = blockIdx.x * 64;

    for (int i = tid; i < 64 * 64; i += 256)
        sw2[(i >> 6) * 72 + (i & 63)] = f2bf(w2f[i]);
    if (tid < 192) {
        sw1[(tid / 3) * 4 + tid % 3] = f2bf(w1f[tid]);
        sx [(tid / 3) * 4 + tid % 3] = f2bf(xf[p0 * 3 + tid]);
    }
    __syncthreads();

    {   // L1 via VALU (K=3)
        int m = tid & 63, ng = tid >> 6;
        float x0 = bf2f(sx[m * 4]), x1 = bf2f(sx[m * 4 + 1]), x2 = bf2f(sx[m * 4 + 2]);
        #pragma unroll
        for (int j = 0; j < 16; ++j) {
            int n = ng * 16 + j;
            float s = x0 * bf2f(sw1[n * 4]) + x1 * bf2f(sw1[n * 4 + 1]) + x2 * bf2f(sw1[n * 4 + 2]);
            shA[m * 72 + n] = f2bf(fmaxf(s, 0.f));
        }
    }
    __syncthreads();

    const int lane = tid & 63, w = tid >> 6, q = lane >> 4, l15 = lane & 15;
    const int mrow = 16 * w;

    f32x4 acc2[4];
    #pragma unroll
    for (int nt = 0; nt < 4; ++nt) acc2[nt] = (f32x4){0.f, 0.f, 0.f, 0.f};
    #pragma unroll
    for (int s = 0; s < 2; ++s) {
        bf16x8 a = *(const bf16x8*)&shA[(mrow + l15) * 72 + s * 32 + q * 8];
        #pragma unroll
        for (int nt = 0; nt < 4; ++nt) {
            bf16x8 b = *(const bf16x8*)&sw2[(nt * 16 + l15) * 72 + s * 32 + q * 8];
            acc2[nt] = MFMA16(a, b, acc2[nt]);
        }
    }
    #pragma unroll
    for (int nt = 0; nt < 4; ++nt)
        #pragma unroll
        for (int r = 0; r < 4; ++r) {
            int m = mrow + q * 4 + r;
            sh2[m * 72 + nt * 16 + l15] = f2bf(fmaxf(acc2[nt][r], 0.f));
        }
    __syncthreads();

    {
        int row = tid >> 2, c = (tid & 3) * 16;
        *(u16x8*)&h2g_buf[(size_t)p0 * 64 + tid * 16]     = *(const u16x8*)&sh2[row * 72 + c];
        *(u16x8*)&h2g_buf[(size_t)p0 * 64 + tid * 16 + 8] = *(const u16x8*)&sh2[row * 72 + c + 8];
    }
}

// ---------------------------------------------------------------------------
// k3 v7: one block per 128-row tile (grid 2048), gather fused, cg-loop.
//   Changes vs v6 (191us, MfmaUtil 30%, FETCH 132MB):
//   (a) col-groups merged into the block: mlp5 loops cg=0..3 -> the 4x
//       redundant A-staging and P4/P5 recompute are gone (FETCH /4, 15%
//       of MFMA work eliminated).
//   (b) wave re-tiling for mlp5: 8 waves each own 32 COLS x all 128 rows
//       (acc[8][2], a[8] frags from LDS, b[2] frags from L2) -> no two
//       waves load the same w5t fragment (v6's mw-pairs duplicated B; L2
//       B-traffic halves to ~0.8GB).
//   (c) k2_pool FUSED: p0 (neighbor-max) is computed in-kernel by 16-way
//       gather from h2g_buf + packed-u16 tree max (valid: post-relu bf16
//       >= 0).  gm_buf (67MB HBM round-trip) and the separate kernel are
//       deleted.  Gather latency hides under the co-resident block's mlp5
//       (LDS 72KB -> 2 blocks/CU, 16 waves).
//   Flow: gather->p0 | stage h2->p1, w3,w4 -> bar -> P4 (h3->p2, wave-local
//   rows) -> P5 (h4 -> p1 lo / p2 hi, wave-local) -> bar -> for cg: mlp5
//   (A from planes, B from w5t/L2) -> col-max reduce -> atomics.
//   Swizzle per 64-col plane: chunk j of row r at ((j^r)&7)*8 (2-way bank
//   alias = free; 0 conflicts measured through v6).
// ---------------------------------------------------------------------------
__global__ __launch_bounds__(512) void k3_fused(const int* __restrict__ idx,
                                                int* __restrict__ gout)
{
    __shared__ __align__(16) u16 lds[36864];      // 72 KB
    u16* p0  = lds;                               // gather-max [128][64]
    u16* p1  = lds + 8192;                        // h2 -> h4 lo
    u16* p2  = lds + 16384;                       // h3 -> h4 hi
    u16* sw3 = lds + 24576;                       // [64][64]
    u16* sw4 = lds + 28672;                       // [128][64]

    const int tid  = threadIdx.x;
    const int lane = tid & 63, w = tid >> 6, q = lane >> 4, l15 = lane & 15;
    const size_t R0 = (size_t)blockIdx.x * 128;

    // ---- fused k2: neighbor gather-max -> p0 (2 tasks/thread) ----
    #pragma unroll
    for (int c = 0; c < 2; ++c) {
        int task = c * 512 + tid;
        int r = task >> 3, jc = task & 7;
        const int* ip = &idx[(R0 + r) * 16];
        u16x8 v[16];
        #pragma unroll
        for (int k = 0; k < 16; ++k)
            v[k] = *(const u16x8*)&h2g_buf[(size_t)ip[k] * 64 + jc * 8];
        #pragma unroll
        for (int o = 8; o; o >>= 1)
            #pragma unroll
            for (int k = 0; k < o; ++k) v[k] = maxu16(v[k], v[k + o]);
        *(u16x8*)&p0[r * 64 + ((jc ^ r) & 7) * 8] = v[0];
    }

    // ---- stage h2 -> p1, w3/w4 ----
    {
        int r = tid >> 3, js = tid & 7;
        *(u16x8*)&sw3[r * 64 + ((js ^ r) & 7) * 8] = *(const u16x8*)&w3b[r * 64 + js * 8];
        #pragma unroll
        for (int c = 0; c < 2; ++c) {
            int i = c * 512 + tid, r4 = i >> 3, j4 = i & 7;
            *(u16x8*)&sw4[r4 * 64 + ((j4 ^ r4) & 7) * 8] = *(const u16x8*)&w4b[r4 * 64 + j4 * 8];
        }
        #pragma unroll
        for (int c = 0; c < 2; ++c) {
            int i = c * 512 + tid, ra = i >> 3, ja = i & 7;
            *(u16x8*)&p1[ra * 64 + ((ja ^ ra) & 7) * 8] =
                *(const u16x8*)&h2g_buf[(R0 + ra) * 64 + ja * 8];
        }
    }
    __syncthreads();

    // ---- P4: h3 = relu(h2 @ w3^T) -> p2 (wave-local rows w*16..+15) ----
    {
        f32x4 a3[4];
        #pragma unroll
        for (int nt = 0; nt < 4; ++nt) a3[nt] = (f32x4){0.f, 0.f, 0.f, 0.f};
        #pragma unroll
        for (int ss = 0; ss < 2; ++ss) {
            int js = ss * 4 + q, r = w * 16 + l15;
            bf16x8 a = *(const bf16x8*)&p1[r * 64 + ((js ^ r) & 7) * 8];
            #pragma unroll
            for (int nt = 0; nt < 4; ++nt) {
                int rw = nt * 16 + l15;
                bf16x8 b = *(const bf16x8*)&sw3[rw * 64 + ((js ^ rw) & 7) * 8];
                a3[nt] = MFMA16(a, b, a3[nt]);
            }
        }
        #pragma unroll
        for (int nt = 0; nt < 4; ++nt)
            #pragma unroll
            for (int r = 0; r < 4; ++r) {
                int m = w * 16 + q * 4 + r;
                int n = nt * 16 + l15;
                p2[m * 64 + (((n >> 3) ^ m) & 7) * 8 + (n & 7)] =
                    f2bf(fmaxf(a3[nt][r], 0.f));
            }
    }
    // no barrier: P4 writes and P5 reads are wave-local rows

    // ---- P5: h4 = relu(h3 @ w4^T) -> p1 (cols 0..63), p2 (cols 64..127) ----
    {
        f32x4 a4[8];
        #pragma unroll
        for (int nt = 0; nt < 8; ++nt) a4[nt] = (f32x4){0.f, 0.f, 0.f, 0.f};
        #pragma unroll
        for (int ss = 0; ss < 2; ++ss) {
            int js = ss * 4 + q, r = w * 16 + l15;
            bf16x8 a = *(const bf16x8*)&p2[r * 64 + ((js ^ r) & 7) * 8];
            #pragma unroll
            for (int nt = 0; nt < 8; ++nt) {
                int rw = nt * 16 + l15;
                bf16x8 b = *(const bf16x8*)&sw4[rw * 64 + ((js ^ rw) & 7) * 8];
                a4[nt] = MFMA16(a, b, a4[nt]);
            }
        }
        #pragma unroll
        for (int nt = 0; nt < 8; ++nt)
            #pragma unroll
            for (int r = 0; r < 4; ++r) {
                int m  = w * 16 + q * 4 + r;
                int n4 = nt * 16 + l15;
                int j  = (n4 >> 3) & 7;
                u16* dp = (nt < 4) ? p1 : p2;
                dp[m * 64 + ((j ^ m) & 7) * 8 + (n4 & 7)] = f2bf(fmaxf(a4[nt][r], 0.f));
            }
    }
    __syncthreads();   // h4 visible to all waves

    // ---- mlp5: wave owns 32 cols x 128 rows; loop cg over 4 col-groups ----
    #pragma unroll 1
    for (int cg = 0; cg < 4; ++cg) {
        f32x4 acc[8][2];
        #pragma unroll
        for (int mt = 0; mt < 8; ++mt)
            #pragma unroll
            for (int nt = 0; nt < 2; ++nt) acc[mt][nt] = (f32x4){0.f, 0.f, 0.f, 0.f};
        #pragma unroll
        for (int s = 0; s < 6; ++s) {
            const u16* pa = (s < 2) ? p0 : ((s < 4) ? p1 : p2);
            int j = (s & 1) * 4 + q;
            bf16x8 b[2];
            #pragma unroll
            for (int nt = 0; nt < 2; ++nt)
                b[nt] = *(const bf16x8*)&w5t[(size_t)(((cg * 16 + w * 2 + nt) * 6 + s)) * 512 + lane * 8];
            bf16x8 a[8];
            #pragma unroll
            for (int mt = 0; mt < 8; ++mt) {
                int r = mt * 16 + l15;
                a[mt] = *(const bf16x8*)&pa[r * 64 + ((j ^ r) & 7) * 8];
            }
            #pragma unroll
            for (int mt = 0; mt < 8; ++mt)
                #pragma unroll
                for (int nt = 0; nt < 2; ++nt)
                    acc[mt][nt] = MFMA16(a[mt], b[nt], acc[mt][nt]);
        }

        // ---- column-max reduce + atomics (relu folded into 0-init) ----
        #pragma unroll
        for (int nt = 0; nt < 2; ++nt) {
            float mx = 0.f;
            #pragma unroll
            for (int mt = 0; mt < 8; ++mt)
                #pragma unroll
                for (int e = 0; e < 4; ++e) mx = fmaxf(mx, acc[mt][nt][e]);
            mx = fmaxf(mx, __shfl_xor(mx, 16, 64));
            mx = fmaxf(mx, __shfl_xor(mx, 32, 64));
            if (q == 0)
                atomicMax(&gout[cg * 256 + w * 32 + nt * 16 + l15], __float_as_int(mx));
        }
    }
}

// ---------------------------------------------------------------------------
// k4: classifier head, pure f32. One wave per output row.
// ---------------------------------------------------------------------------
__global__ void k4_f1(const float* __restrict__ wf1)
{
    int r = blockIdx.x, l = threadIdx.x;
    float s = 0.f;
    #pragma unroll
    for (int i = 0; i < 16; ++i) s += wf1[r * 1024 + i * 64 + l] * g_buf[i * 64 + l];
    #pragma unroll
    for (int o = 32; o; o >>= 1) s += __shfl_down(s, o, 64);
    if (!l) f1_buf[r] = fmaxf(s, 0.f);
}
__global__ void k4_f2(const float* __restrict__ wf2)
{
    int r = blockIdx.x, l = threadIdx.x;
    float s = 0.f;
    #pragma unroll
    for (int i = 0; i < 8; ++i) s += wf2[r * 512 + i * 64 + l] * f1_buf[i * 64 + l];
    #pragma unroll
    for (int o = 32; o; o >>= 1) s += __shfl_down(s, o, 64);
    if (!l) f2_buf[r] = fmaxf(s, 0.f);
}
__global__ void k4_out(const float* __restrict__ wf3, float* __restrict__ out)
{
    int r = blockIdx.x, l = threadIdx.x;
    float s = 0.f;
    #pragma unroll
    for (int i = 0; i < 4; ++i) s += wf3[r * 256 + i * 64 + l] * f2_buf[i * 64 + l];
    #pragma unroll
    for (int o = 32; o; o >>= 1) s += __shfl_down(s, o, 64);
    if (!l) out[r] = s;
}

// ---------------------------------------------------------------------------
extern "C" void kernel_launch(void* const* d_in, const int* in_sizes, int n_in,
                              void* d_out, int out_size, void* d_ws, size_t ws_size,
                              hipStream_t stream)
{
    (void)in_sizes; (void)n_in; (void)out_size; (void)d_ws; (void)ws_size;
    const float* x   = (const float*)d_in[0];
    const int*   idx = (const int*)d_in[2];
    const float* w1  = (const float*)d_in[3];
    const float* w2  = (const float*)d_in[4];
    const float* w3  = (const float*)d_in[5];
    const float* w4  = (const float*)d_in[6];
    const float* w5  = (const float*)d_in[7];
    const float* wf1 = (const float*)d_in[8];
    const float* wf2 = (const float*)d_in[9];
    const float* wf3 = (const float*)d_in[10];

    float* gptr;
    hipGetSymbolAddress((void**)&gptr, HIP_SYMBOL(g_buf));

    k0_zero <<<1, 1024, 0, stream>>>();
    kcvt    <<<816, 256, 0, stream>>>(w3, w4, w5);
    k1_mlp  <<<262144 / 64, 256, 0, stream>>>(x, w1, w2);
    k3_fused<<<2048, 512, 0, stream>>>(idx, (int*)gptr);
    k4_f1   <<<512, 64, 0, stream>>>(wf1);
    k4_f2   <<<256, 64, 0, stream>>>(wf2);
    k4_out  <<<40, 64, 0, stream>>>(wf3, (float*)d_out);
}

// Round 7
// 387.955 us; speedup vs baseline: 1.2227x; 1.2227x over previous
//
#include <hip/hip_runtime.h>
#include <hip/hip_bf16.h>
#include <stdint.h>

typedef unsigned short u16;
typedef __bf16 bf16x8 __attribute__((ext_vector_type(8)));
typedef float  f32x4  __attribute__((ext_vector_type(4)));
typedef u16    u16x8  __attribute__((ext_vector_type(8)));

__device__ __forceinline__ float bf2f(u16 u) {
    return __uint_as_float(((unsigned)u) << 16);
}
__device__ __forceinline__ u16 f2bf(float f) {   // round-to-nearest-even
    unsigned u = __float_as_uint(f);
    u += 0x7fffu + ((u >> 16) & 1u);
    return (u16)(u >> 16);
}
__device__ __forceinline__ u16x8 maxu16(u16x8 a, u16x8 b) {
    u16x8 r;
    #pragma unroll
    for (int e = 0; e < 8; ++e) r[e] = a[e] > b[e] ? a[e] : b[e];
    return r;
}

#define MFMA16(a, b, c) __builtin_amdgcn_mfma_f32_16x16x32_bf16(a, b, c, 0, 0, 0)

// Static device buffers — no d_ws dependency.
__device__ u16   h2g_buf[262144 * 64];   // h2 [N][64] bf16 (33.5 MB)
__device__ u16   gm_buf [262144 * 64];   // neighbor-max [N][64] bf16 (33.5 MB)
__device__ u16   w3b[64 * 64];           // weights pre-converted to bf16
__device__ u16   w4b[128 * 64];
// w5 transposed to MFMA-fragment-contiguous layout:
//   w5t[((c16*6 + s)*64 + lane)*8 + e] = w5[c16*16 + (lane&15)][s*32 + (lane>>4)*8 + e]
// so a wave's B-frag load for (c16, s) is one fully-coalesced 1KB read.
__device__ u16   w5t[64 * 6 * 64 * 8];   // 384 KB, L2-resident per XCD
__device__ float g_buf[1024];            // global column max (>= 0)
__device__ float f1_buf[512];
__device__ float f2_buf[256];

// ---------------------------------------------------------------------------
__global__ void k0_zero() { g_buf[threadIdx.x] = 0.f; }

__global__ void kcvt(const float* __restrict__ w3f, const float* __restrict__ w4f,
                     const float* __restrict__ w5f)
{
    int i = blockIdx.x * 256 + threadIdx.x;     // 816*256 = 208896 = 4096+8192+196608
    if (i < 4096)        w3b[i]        = f2bf(w3f[i]);
    else if (i < 12288)  w4b[i - 4096] = f2bf(w4f[i - 4096]);
    else {
        int o    = i - 12288;                   // 0..196607
        int e    = o & 7;
        int lane = (o >> 3) & 63;
        int sg   = o >> 9;                      // c16*6 + s
        int s    = sg % 6, c16 = sg / 6;
        int q    = lane >> 4, l15 = lane & 15;
        w5t[o] = f2bf(w5f[(c16 * 16 + l15) * 192 + s * 32 + q * 8 + e]);
    }
}

// ---------------------------------------------------------------------------
// k1: mlp1+mlp2 for 64 points/block (f32 in -> bf16). Writes h2g_buf.
// ---------------------------------------------------------------------------
__global__ __launch_bounds__(256) void k1_mlp(
    const float* __restrict__ xf, const float* __restrict__ w1f,
    const float* __restrict__ w2f)
{
    __shared__ __align__(16) u16 sw1[64 * 4];
    __shared__ __align__(16) u16 sx [64 * 4];
    __shared__ __align__(16) u16 sw2[64 * 72];
    __shared__ __align__(16) u16 shA[64 * 72];
    __shared__ __align__(16) u16 sh2[64 * 72];

    const int tid = threadIdx.x;
    const int p0  = blockIdx.x * 64;

    for (int i = tid; i < 64 * 64; i += 256)
        sw2[(i >> 6) * 72 + (i & 63)] = f2bf(w2f[i]);
    if (tid < 192) {
        sw1[(tid / 3) * 4 + tid % 3] = f2bf(w1f[tid]);
        sx [(tid / 3) * 4 + tid % 3] = f2bf(xf[p0 * 3 + tid]);
    }
    __syncthreads();

    {   // L1 via VALU (K=3)
        int m = tid & 63, ng = tid >> 6;
        float x0 = bf2f(sx[m * 4]), x1 = bf2f(sx[m * 4 + 1]), x2 = bf2f(sx[m * 4 + 2]);
        #pragma unroll
        for (int j = 0; j < 16; ++j) {
            int n = ng * 16 + j;
            float s = x0 * bf2f(sw1[n * 4]) + x1 * bf2f(sw1[n * 4 + 1]) + x2 * bf2f(sw1[n * 4 + 2]);
            shA[m * 72 + n] = f2bf(fmaxf(s, 0.f));
        }
    }
    __syncthreads();

    const int lane = tid & 63, w = tid >> 6, q = lane >> 4, l15 = lane & 15;
    const int mrow = 16 * w;

    f32x4 acc2[4];
    #pragma unroll
    for (int nt = 0; nt < 4; ++nt) acc2[nt] = (f32x4){0.f, 0.f, 0.f, 0.f};
    #pragma unroll
    for (int s = 0; s < 2; ++s) {
        bf16x8 a = *(const bf16x8*)&shA[(mrow + l15) * 72 + s * 32 + q * 8];
        #pragma unroll
        for (int nt = 0; nt < 4; ++nt) {
            bf16x8 b = *(const bf16x8*)&sw2[(nt * 16 + l15) * 72 + s * 32 + q * 8];
            acc2[nt] = MFMA16(a, b, acc2[nt]);
        }
    }
    #pragma unroll
    for (int nt = 0; nt < 4; ++nt)
        #pragma unroll
        for (int r = 0; r < 4; ++r) {
            int m = mrow + q * 4 + r;
            sh2[m * 72 + nt * 16 + l15] = f2bf(fmaxf(acc2[nt][r], 0.f));
        }
    __syncthreads();

    {
        int row = tid >> 2, c = (tid & 3) * 16;
        *(u16x8*)&h2g_buf[(size_t)p0 * 64 + tid * 16]     = *(const u16x8*)&sh2[row * 72 + c];
        *(u16x8*)&h2g_buf[(size_t)p0 * 64 + tid * 16 + 8] = *(const u16x8*)&sh2[row * 72 + c + 8];
    }
}

// ---------------------------------------------------------------------------
// k2_pool: 8 threads per point (thread owns a 16B channel chunk). 16
//   INDEPENDENT gather loads issued back-to-back per thread, local packed-u16
//   max (valid: post-relu bf16 >= 0), direct 16B store.  Restored from v6
//   after the v7 fusion regressed (gather lost its high-occupancy TLP and
//   serialized before mlp5 behind a barrier).
// ---------------------------------------------------------------------------
__global__ __launch_bounds__(256) void k2_pool(const int* __restrict__ idx)
{
    const size_t gt = (size_t)blockIdx.x * 256 + threadIdx.x;
    const size_t p  = gt >> 3;              // point
    const int    c  = (threadIdx.x & 7) * 8; // channel chunk

    u16x8 v[16];
    #pragma unroll
    for (int k = 0; k < 16; ++k) {
        int j = idx[p * 16 + k];
        v[k] = *(const u16x8*)&h2g_buf[(size_t)j * 64 + c];
    }
    u16x8 m = v[0];
    #pragma unroll
    for (int k = 1; k < 16; ++k) m = maxu16(m, v[k]);
    *(u16x8*)&gm_buf[p * 64 + c] = m;
}

// ---------------------------------------------------------------------------
// k3 v8: v6 structure + cg-merge, NO gather fusion.
//   v7 post-mortem: (1) the cg loop's A-frag loads are cg-invariant, LICM
//   hoisted 48 frags (~192 VGPR) -> spill (VGPR=128, WRITE 252MB).  Fixed
//   by an asm-volatile redefinition of a zero offset INSIDE the cg loop,
//   folded into every A-frag address -> addresses not loop-invariant ->
//   hoist structurally impossible.  (2) gather fusion starved the gather of
//   TLP; reverted to standalone k2_pool.
//   Grid 2048 (one block per 128-row tile), 512 thr (8 waves).
//   Stage(gm,h2,w3,w4) -> bar -> P4 (h3->p2, wave-local rows) -> P5 (h4 ->
//   p1 lo / p2 hi, wave-local) -> bar -> for cg in 0..3: mlp5 where each
//   wave owns 32 DISTINCT cols (acc[8][2], a[8] from LDS, b[2] from w5t/L2;
//   no wave-pair B duplication -> L2 B-traffic halved vs v6) -> col-max
//   reduce -> atomics.  A-staging and P4/P5 now run ONCE per row-tile
//   (v6 ran them 4x, once per cg block): -19 GFLOP MFMA, -3/4 staging and
//   f2bf VALU, FETCH 132MB -> ~40MB.
//   LDS 72KB -> 2 blocks/CU, 16 waves/CU.  Swizzle per 64-col plane:
//   chunk j of row r at ((j^r)&7)*8 (2-way bank alias = free).
// ---------------------------------------------------------------------------
__global__ __launch_bounds__(512) void k3_fused(int* __restrict__ gout)
{
    __shared__ __align__(16) u16 lds[36864];      // 72 KB
    u16* p0  = lds;                               // gather-max [128][64]
    u16* p1  = lds + 8192;                        // h2 -> h4 lo
    u16* p2  = lds + 16384;                       // h3 -> h4 hi
    u16* sw3 = lds + 24576;                       // [64][64]
    u16* sw4 = lds + 28672;                       // [128][64]

    const int tid  = threadIdx.x;
    const int lane = tid & 63, w = tid >> 6, q = lane >> 4, l15 = lane & 15;
    const size_t R0 = (size_t)blockIdx.x * 128;

    // ---- stage gm -> p0, h2 -> p1, w3/w4 ----
    {
        int r = tid >> 3, js = tid & 7;
        *(u16x8*)&sw3[r * 64 + ((js ^ r) & 7) * 8] = *(const u16x8*)&w3b[r * 64 + js * 8];
        #pragma unroll
        for (int c = 0; c < 2; ++c) {
            int i = c * 512 + tid, r4 = i >> 3, j4 = i & 7;
            *(u16x8*)&sw4[r4 * 64 + ((j4 ^ r4) & 7) * 8] = *(const u16x8*)&w4b[r4 * 64 + j4 * 8];
        }
        #pragma unroll
        for (int c = 0; c < 2; ++c) {
            int i = c * 512 + tid, ra = i >> 3, ja = i & 7;
            *(u16x8*)&p0[ra * 64 + ((ja ^ ra) & 7) * 8] =
                *(const u16x8*)&gm_buf[(R0 + ra) * 64 + ja * 8];
            *(u16x8*)&p1[ra * 64 + ((ja ^ ra) & 7) * 8] =
                *(const u16x8*)&h2g_buf[(R0 + ra) * 64 + ja * 8];
        }
    }
    __syncthreads();

    // ---- P4: h3 = relu(h2 @ w3^T) -> p2 (wave-local rows w*16..+15) ----
    {
        f32x4 a3[4];
        #pragma unroll
        for (int nt = 0; nt < 4; ++nt) a3[nt] = (f32x4){0.f, 0.f, 0.f, 0.f};
        #pragma unroll
        for (int ss = 0; ss < 2; ++ss) {
            int js = ss * 4 + q, r = w * 16 + l15;
            bf16x8 a = *(const bf16x8*)&p1[r * 64 + ((js ^ r) & 7) * 8];
            #pragma unroll
            for (int nt = 0; nt < 4; ++nt) {
                int rw = nt * 16 + l15;
                bf16x8 b = *(const bf16x8*)&sw3[rw * 64 + ((js ^ rw) & 7) * 8];
                a3[nt] = MFMA16(a, b, a3[nt]);
            }
        }
        #pragma unroll
        for (int nt = 0; nt < 4; ++nt)
            #pragma unroll
            for (int r = 0; r < 4; ++r) {
                int m = w * 16 + q * 4 + r;
                int n = nt * 16 + l15;
                p2[m * 64 + (((n >> 3) ^ m) & 7) * 8 + (n & 7)] =
                    f2bf(fmaxf(a3[nt][r], 0.f));
            }
    }
    // no barrier: P4 writes and P5 reads are wave-local rows

    // ---- P5: h4 = relu(h3 @ w4^T) -> p1 (cols 0..63), p2 (cols 64..127) ----
    {
        f32x4 a4[8];
        #pragma unroll
        for (int nt = 0; nt < 8; ++nt) a4[nt] = (f32x4){0.f, 0.f, 0.f, 0.f};
        #pragma unroll
        for (int ss = 0; ss < 2; ++ss) {
            int js = ss * 4 + q, r = w * 16 + l15;
            bf16x8 a = *(const bf16x8*)&p2[r * 64 + ((js ^ r) & 7) * 8];
            #pragma unroll
            for (int nt = 0; nt < 8; ++nt) {
                int rw = nt * 16 + l15;
                bf16x8 b = *(const bf16x8*)&sw4[rw * 64 + ((js ^ rw) & 7) * 8];
                a4[nt] = MFMA16(a, b, a4[nt]);
            }
        }
        #pragma unroll
        for (int nt = 0; nt < 8; ++nt)
            #pragma unroll
            for (int r = 0; r < 4; ++r) {
                int m  = w * 16 + q * 4 + r;
                int n4 = nt * 16 + l15;
                int j  = (n4 >> 3) & 7;
                u16* dp = (nt < 4) ? p1 : p2;
                dp[m * 64 + ((j ^ m) & 7) * 8 + (n4 & 7)] = f2bf(fmaxf(a4[nt][r], 0.f));
            }
    }
    __syncthreads();   // h4 visible to all waves

    // ---- mlp5: loop cg; wave owns 32 distinct cols x all 128 rows ----
    int zoff = 0;      // stays 0; opaquely redefined per cg iteration below
    #pragma unroll 1
    for (int cg = 0; cg < 4; ++cg) {
        asm volatile("" : "+v"(zoff));   // breaks cg-invariance of A-frag addrs (anti-LICM)
        f32x4 acc[8][2];
        #pragma unroll
        for (int mt = 0; mt < 8; ++mt)
            #pragma unroll
            for (int nt = 0; nt < 2; ++nt) acc[mt][nt] = (f32x4){0.f, 0.f, 0.f, 0.f};
        #pragma unroll
        for (int s = 0; s < 6; ++s) {
            const u16* pa = (s < 2) ? p0 : ((s < 4) ? p1 : p2);
            int j = (s & 1) * 4 + q;
            bf16x8 b[2];
            #pragma unroll
            for (int nt = 0; nt < 2; ++nt)
                b[nt] = *(const bf16x8*)&w5t[(size_t)(((cg * 16 + w * 2 + nt) * 6 + s)) * 512 + lane * 8];
            bf16x8 a[8];
            #pragma unroll
            for (int mt = 0; mt < 8; ++mt) {
                int r = mt * 16 + l15;
                a[mt] = *(const bf16x8*)&pa[r * 64 + ((j ^ r) & 7) * 8 + zoff];
            }
            #pragma unroll
            for (int mt = 0; mt < 8; ++mt)
                #pragma unroll
                for (int nt = 0; nt < 2; ++nt)
                    acc[mt][nt] = MFMA16(a[mt], b[nt], acc[mt][nt]);
        }

        // ---- column-max reduce + atomics (relu folded into 0-init) ----
        #pragma unroll
        for (int nt = 0; nt < 2; ++nt) {
            float mx = 0.f;
            #pragma unroll
            for (int mt = 0; mt < 8; ++mt)
                #pragma unroll
                for (int e = 0; e < 4; ++e) mx = fmaxf(mx, acc[mt][nt][e]);
            mx = fmaxf(mx, __shfl_xor(mx, 16, 64));
            mx = fmaxf(mx, __shfl_xor(mx, 32, 64));
            if (q == 0)
                atomicMax(&gout[cg * 256 + w * 32 + nt * 16 + l15], __float_as_int(mx));
        }
    }
}

// ---------------------------------------------------------------------------
// k4: classifier head, pure f32. One wave per output row.
// ---------------------------------------------------------------------------
__global__ void k4_f1(const float* __restrict__ wf1)
{
    int r = blockIdx.x, l = threadIdx.x;
    float s = 0.f;
    #pragma unroll
    for (int i = 0; i < 16; ++i) s += wf1[r * 1024 + i * 64 + l] * g_buf[i * 64 + l];
    #pragma unroll
    for (int o = 32; o; o >>= 1) s += __shfl_down(s, o, 64);
    if (!l) f1_buf[r] = fmaxf(s, 0.f);
}
__global__ void k4_f2(const float* __restrict__ wf2)
{
    int r = blockIdx.x, l = threadIdx.x;
    float s = 0.f;
    #pragma unroll
    for (int i = 0; i < 8; ++i) s += wf2[r * 512 + i * 64 + l] * f1_buf[i * 64 + l];
    #pragma unroll
    for (int o = 32; o; o >>= 1) s += __shfl_down(s, o, 64);
    if (!l) f2_buf[r] = fmaxf(s, 0.f);
}
__global__ void k4_out(const float* __restrict__ wf3, float* __restrict__ out)
{
    int r = blockIdx.x, l = threadIdx.x;
    float s = 0.f;
    #pragma unroll
    for (int i = 0; i < 4; ++i) s += wf3[r * 256 + i * 64 + l] * f2_buf[i * 64 + l];
    #pragma unroll
    for (int o = 32; o; o >>= 1) s += __shfl_down(s, o, 64);
    if (!l) out[r] = s;
}

// ---------------------------------------------------------------------------
extern "C" void kernel_launch(void* const* d_in, const int* in_sizes, int n_in,
                              void* d_out, int out_size, void* d_ws, size_t ws_size,
                              hipStream_t stream)
{
    (void)in_sizes; (void)n_in; (void)out_size; (void)d_ws; (void)ws_size;
    const float* x   = (const float*)d_in[0];
    const int*   idx = (const int*)d_in[2];
    const float* w1  = (const float*)d_in[3];
    const float* w2  = (const float*)d_in[4];
    const float* w3  = (const float*)d_in[5];
    const float* w4  = (const float*)d_in[6];
    const float* w5  = (const float*)d_in[7];
    const float* wf1 = (const float*)d_in[8];
    const float* wf2 = (const float*)d_in[9];
    const float* wf3 = (const float*)d_in[10];

    float* gptr;
    hipGetSymbolAddress((void**)&gptr, HIP_SYMBOL(g_buf));

    k0_zero <<<1, 1024, 0, stream>>>();
    kcvt    <<<816, 256, 0, stream>>>(w3, w4, w5);
    k1_mlp  <<<262144 / 64, 256, 0, stream>>>(x, w1, w2);
    k2_pool <<<262144 * 8 / 256, 256, 0, stream>>>(idx);
    k3_fused<<<2048, 512, 0, stream>>>((int*)gptr);
    k4_f1   <<<512, 64, 0, stream>>>(wf1);
    k4_f2   <<<256, 64, 0, stream>>>(wf2);
    k4_out  <<<40, 64, 0, stream>>>(wf3, (float*)d_out);
}

// Round 8
// 384.358 us; speedup vs baseline: 1.2341x; 1.0094x over previous
//
#include <hip/hip_runtime.h>
#include <hip/hip_bf16.h>
#include <stdint.h>

typedef unsigned short u16;
typedef __bf16 bf16x8 __attribute__((ext_vector_type(8)));
typedef float  f32x4  __attribute__((ext_vector_type(4)));
typedef float  f32x16 __attribute__((ext_vector_type(16)));
typedef u16    u16x8  __attribute__((ext_vector_type(8)));

__device__ __forceinline__ float bf2f(u16 u) {
    return __uint_as_float(((unsigned)u) << 16);
}
__device__ __forceinline__ u16 f2bf(float f) {   // round-to-nearest-even
    unsigned u = __float_as_uint(f);
    u += 0x7fffu + ((u >> 16) & 1u);
    return (u16)(u >> 16);
}
__device__ __forceinline__ u16x8 maxu16(u16x8 a, u16x8 b) {
    u16x8 r;
    #pragma unroll
    for (int e = 0; e < 8; ++e) r[e] = a[e] > b[e] ? a[e] : b[e];
    return r;
}

#define MFMA16(a, b, c) __builtin_amdgcn_mfma_f32_16x16x32_bf16(a, b, c, 0, 0, 0)
#define MFMA32(a, b, c) __builtin_amdgcn_mfma_f32_32x32x16_bf16(a, b, c, 0, 0, 0)

// Static device buffers — no d_ws dependency.
__device__ u16   h2g_buf[262144 * 64];   // h2 [N][64] bf16 (33.5 MB)
__device__ u16   gm_buf [262144 * 64];   // neighbor-max [N][64] bf16 (33.5 MB)
__device__ u16   w1b[64 * 3];            // weights pre-converted to bf16
__device__ u16   w2b[64 * 64];
__device__ u16   w3b[64 * 64];
__device__ u16   w4b[128 * 64];
// w5 transposed for the 32x32x16 MFMA B-fragment:
//   g = 32-col group (0..31), ks = K/16 slice (0..11), lane 0..63, e 0..7
//   w5t[((g*12 + ks)*64 + lane)*8 + e] =
//       w5[g*32 + (lane&31)][ks*16 + (lane>>5)*8 + e]
// so a wave's B-frag load for (g, ks) is one fully-coalesced 1KB read.
__device__ u16   w5t[32 * 12 * 64 * 8]; // 384 KB, L2-resident per XCD
__device__ float g_buf[1024];            // global column max (>= 0)
__device__ float f1_buf[512];
__device__ float f2_buf[256];

// ---------------------------------------------------------------------------
__global__ void k0_zero() { g_buf[threadIdx.x] = 0.f; }

__global__ void kcvt(const float* __restrict__ w1f, const float* __restrict__ w2f,
                     const float* __restrict__ w3f, const float* __restrict__ w4f,
                     const float* __restrict__ w5f)
{
    int i = blockIdx.x * 256 + threadIdx.x;     // 833*256 = 213248 >= 213184
    if (i < 4096)        w3b[i]         = f2bf(w3f[i]);
    else if (i < 12288)  w4b[i - 4096]  = f2bf(w4f[i - 4096]);
    else if (i < 12480)  w1b[i - 12288] = f2bf(w1f[i - 12288]);
    else if (i < 16576)  w2b[i - 12480] = f2bf(w2f[i - 12480]);
    else if (i < 213184) {
        int o    = i - 16576;                   // 0..196607
        int e    = o & 7;
        int lane = (o >> 3) & 63;
        int gks  = o >> 9;                      // g*12 + ks
        int ks   = gks % 12, g = gks / 12;
        int col  = g * 32 + (lane & 31);
        int k    = ks * 16 + (lane >> 5) * 8 + e;
        w5t[o] = f2bf(w5f[col * 192 + k]);
    }
}

// ---------------------------------------------------------------------------
// k1: mlp1+mlp2 for 64 points/block (f32 in -> bf16). Writes h2g_buf.
//   v9: w1/w2 pre-converted in kcvt -> staging is pure bf16 vector copy
//   (removes 16.8M f2bf VALU ops and 67MB of f32 w2 L2 reads).
// ---------------------------------------------------------------------------
__global__ __launch_bounds__(256) void k1_mlp(const float* __restrict__ xf)
{
    __shared__ __align__(16) u16 sw1[64 * 4];
    __shared__ __align__(16) u16 sx [64 * 4];
    __shared__ __align__(16) u16 sw2[64 * 72];
    __shared__ __align__(16) u16 shA[64 * 72];
    __shared__ __align__(16) u16 sh2[64 * 72];

    const int tid = threadIdx.x;
    const int p0  = blockIdx.x * 64;

    #pragma unroll
    for (int c = 0; c < 2; ++c) {
        int ch = c * 256 + tid;                 // 512 chunks of 8
        int row = ch >> 3, j = ch & 7;
        *(u16x8*)&sw2[row * 72 + j * 8] = *(const u16x8*)&w2b[row * 64 + j * 8];
    }
    if (tid < 192) {
        sw1[(tid / 3) * 4 + tid % 3] = w1b[tid];
        sx [(tid / 3) * 4 + tid % 3] = f2bf(xf[p0 * 3 + tid]);
    }
    __syncthreads();

    {   // L1 via VALU (K=3)
        int m = tid & 63, ng = tid >> 6;
        float x0 = bf2f(sx[m * 4]), x1 = bf2f(sx[m * 4 + 1]), x2 = bf2f(sx[m * 4 + 2]);
        #pragma unroll
        for (int j = 0; j < 16; ++j) {
            int n = ng * 16 + j;
            float s = x0 * bf2f(sw1[n * 4]) + x1 * bf2f(sw1[n * 4 + 1]) + x2 * bf2f(sw1[n * 4 + 2]);
            shA[m * 72 + n] = f2bf(fmaxf(s, 0.f));
        }
    }
    __syncthreads();

    const int lane = tid & 63, w = tid >> 6, q = lane >> 4, l15 = lane & 15;
    const int mrow = 16 * w;

    f32x4 acc2[4];
    #pragma unroll
    for (int nt = 0; nt < 4; ++nt) acc2[nt] = (f32x4){0.f, 0.f, 0.f, 0.f};
    #pragma unroll
    for (int s = 0; s < 2; ++s) {
        bf16x8 a = *(const bf16x8*)&shA[(mrow + l15) * 72 + s * 32 + q * 8];
        #pragma unroll
        for (int nt = 0; nt < 4; ++nt) {
            bf16x8 b = *(const bf16x8*)&sw2[(nt * 16 + l15) * 72 + s * 32 + q * 8];
            acc2[nt] = MFMA16(a, b, acc2[nt]);
        }
    }
    #pragma unroll
    for (int nt = 0; nt < 4; ++nt)
        #pragma unroll
        for (int r = 0; r < 4; ++r) {
            int m = mrow + q * 4 + r;
            sh2[m * 72 + nt * 16 + l15] = f2bf(fmaxf(acc2[nt][r], 0.f));
        }
    __syncthreads();

    {
        int row = tid >> 2, c = (tid & 3) * 16;
        *(u16x8*)&h2g_buf[(size_t)p0 * 64 + tid * 16]     = *(const u16x8*)&sh2[row * 72 + c];
        *(u16x8*)&h2g_buf[(size_t)p0 * 64 + tid * 16 + 8] = *(const u16x8*)&sh2[row * 72 + c + 8];
    }
}

// ---------------------------------------------------------------------------
// k2_pool: 8 threads per point (thread owns a 16B channel chunk). 16
//   INDEPENDENT gather loads issued back-to-back per thread, local packed-u16
//   max (valid: post-relu bf16 >= 0), direct 16B store.  ~537MB of LLC-
//   resident gather traffic (16x re-read of h2g_buf) — near intrinsic floor.
// ---------------------------------------------------------------------------
__global__ __launch_bounds__(256) void k2_pool(const int* __restrict__ idx)
{
    const size_t gt = (size_t)blockIdx.x * 256 + threadIdx.x;
    const size_t p  = gt >> 3;              // point
    const int    c  = (threadIdx.x & 7) * 8; // channel chunk

    u16x8 v[16];
    #pragma unroll
    for (int k = 0; k < 16; ++k) {
        int j = idx[p * 16 + k];
        v[k] = *(const u16x8*)&h2g_buf[(size_t)j * 64 + c];
    }
    u16x8 m = v[0];
    #pragma unroll
    for (int k = 1; k < 16; ++k) m = maxu16(m, v[k]);
    *(u16x8*)&gm_buf[p * 64 + c] = m;
}

// ---------------------------------------------------------------------------
// k3 v9: v8 structure; mlp5 switched to 32x32x16 MFMA.
//   v8 measured: 150us, MfmaUtil 30%, VGPR 56, no spill, FETCH 34.7MB.
//   MFMA busy floor = 103GFLOP/2.5PF = 44us -> issue/latency overhead is
//   the remainder.  32x32x16: half the MFMA instructions (192 vs 384 per
//   wave), ~13% faster pipe (2382 vs 2075 TF ubench), same load traffic
//   (48 a + 12 b ds/global loads per cg either way), same 64 AGPR acc.
//   T5 setprio(1) wrapped around the MFMA cluster (mlp5 waves free-run, the
//   regime where setprio showed +4-7%).  zoff anti-LICM guard retained
//   (a-frag addrs are cg-invariant; proven spill cause in v7).
//   Output mapping for 32x32: col = lane&31 (rows spread over regs and
//   lane>>5 — irrelevant, we col-max-reduce all 16 regs then shfl_xor(32)).
//   Grid 2048 (one block per 128-row tile), 512 thr (8 waves).
//   LDS 72KB -> 2 blocks/CU.  Swizzle per 64-col plane: chunk j of row r
//   at ((j^r)&7)*8 (2-way bank alias = free; 0 conflicts measured).
// ---------------------------------------------------------------------------
__global__ __launch_bounds__(512) void k3_fused(int* __restrict__ gout)
{
    __shared__ __align__(16) u16 lds[36864];      // 72 KB
    u16* p0  = lds;                               // gather-max [128][64]
    u16* p1  = lds + 8192;                        // h2 -> h4 lo
    u16* p2  = lds + 16384;                       // h3 -> h4 hi
    u16* sw3 = lds + 24576;                       // [64][64]
    u16* sw4 = lds + 28672;                       // [128][64]

    const int tid  = threadIdx.x;
    const int lane = tid & 63, w = tid >> 6, q = lane >> 4, l15 = lane & 15;
    const size_t R0 = (size_t)blockIdx.x * 128;

    // ---- stage gm -> p0, h2 -> p1, w3/w4 ----
    {
        int r = tid >> 3, js = tid & 7;
        *(u16x8*)&sw3[r * 64 + ((js ^ r) & 7) * 8] = *(const u16x8*)&w3b[r * 64 + js * 8];
        #pragma unroll
        for (int c = 0; c < 2; ++c) {
            int i = c * 512 + tid, r4 = i >> 3, j4 = i & 7;
            *(u16x8*)&sw4[r4 * 64 + ((j4 ^ r4) & 7) * 8] = *(const u16x8*)&w4b[r4 * 64 + j4 * 8];
        }
        #pragma unroll
        for (int c = 0; c < 2; ++c) {
            int i = c * 512 + tid, ra = i >> 3, ja = i & 7;
            *(u16x8*)&p0[ra * 64 + ((ja ^ ra) & 7) * 8] =
                *(const u16x8*)&gm_buf[(R0 + ra) * 64 + ja * 8];
            *(u16x8*)&p1[ra * 64 + ((ja ^ ra) & 7) * 8] =
                *(const u16x8*)&h2g_buf[(R0 + ra) * 64 + ja * 8];
        }
    }
    __syncthreads();

    // ---- P4: h3 = relu(h2 @ w3^T) -> p2 (wave-local rows w*16..+15) ----
    {
        f32x4 a3[4];
        #pragma unroll
        for (int nt = 0; nt < 4; ++nt) a3[nt] = (f32x4){0.f, 0.f, 0.f, 0.f};
        #pragma unroll
        for (int ss = 0; ss < 2; ++ss) {
            int js = ss * 4 + q, r = w * 16 + l15;
            bf16x8 a = *(const bf16x8*)&p1[r * 64 + ((js ^ r) & 7) * 8];
            #pragma unroll
            for (int nt = 0; nt < 4; ++nt) {
                int rw = nt * 16 + l15;
                bf16x8 b = *(const bf16x8*)&sw3[rw * 64 + ((js ^ rw) & 7) * 8];
                a3[nt] = MFMA16(a, b, a3[nt]);
            }
        }
        #pragma unroll
        for (int nt = 0; nt < 4; ++nt)
            #pragma unroll
            for (int r = 0; r < 4; ++r) {
                int m = w * 16 + q * 4 + r;
                int n = nt * 16 + l15;
                p2[m * 64 + (((n >> 3) ^ m) & 7) * 8 + (n & 7)] =
                    f2bf(fmaxf(a3[nt][r], 0.f));
            }
    }
    // no barrier: P4 writes and P5 reads are wave-local rows

    // ---- P5: h4 = relu(h3 @ w4^T) -> p1 (cols 0..63), p2 (cols 64..127) ----
    {
        f32x4 a4[8];
        #pragma unroll
        for (int nt = 0; nt < 8; ++nt) a4[nt] = (f32x4){0.f, 0.f, 0.f, 0.f};
        #pragma unroll
        for (int ss = 0; ss < 2; ++ss) {
            int js = ss * 4 + q, r = w * 16 + l15;
            bf16x8 a = *(const bf16x8*)&p2[r * 64 + ((js ^ r) & 7) * 8];
            #pragma unroll
            for (int nt = 0; nt < 8; ++nt) {
                int rw = nt * 16 + l15;
                bf16x8 b = *(const bf16x8*)&sw4[rw * 64 + ((js ^ rw) & 7) * 8];
                a4[nt] = MFMA16(a, b, a4[nt]);
            }
        }
        #pragma unroll
        for (int nt = 0; nt < 8; ++nt)
            #pragma unroll
            for (int r = 0; r < 4; ++r) {
                int m  = w * 16 + q * 4 + r;
                int n4 = nt * 16 + l15;
                int j  = (n4 >> 3) & 7;
                u16* dp = (nt < 4) ? p1 : p2;
                dp[m * 64 + ((j ^ m) & 7) * 8 + (n4 & 7)] = f2bf(fmaxf(a4[nt][r], 0.f));
            }
    }
    __syncthreads();   // h4 visible to all waves

    // ---- mlp5: 32x32x16; wave owns 32 cols, 4 row-tiles of 32; loop cg ----
    const int l31 = lane & 31, hi = lane >> 5;
    int zoff = 0;      // stays 0; opaquely redefined per cg iteration below
    #pragma unroll 1
    for (int cg = 0; cg < 4; ++cg) {
        asm volatile("" : "+v"(zoff));   // breaks cg-invariance of A-frag addrs (anti-LICM)
        f32x16 acc[4];
        #pragma unroll
        for (int mt = 0; mt < 4; ++mt) acc[mt] = (f32x16)(0.f);
        #pragma unroll
        for (int ks = 0; ks < 12; ++ks) {
            const u16* pa = (ks < 4) ? p0 : ((ks < 8) ? p1 : p2);
            int j = (ks & 3) * 2 + hi;   // chunk within the 64-col plane
            bf16x8 b = *(const bf16x8*)&w5t[(size_t)((cg * 8 + w) * 12 + ks) * 512 + lane * 8];
            bf16x8 a[4];
            #pragma unroll
            for (int mt = 0; mt < 4; ++mt) {
                int r = mt * 32 + l31;
                a[mt] = *(const bf16x8*)&pa[r * 64 + ((j ^ r) & 7) * 8 + zoff];
            }
            __builtin_amdgcn_s_setprio(1);
            #pragma unroll
            for (int mt = 0; mt < 4; ++mt)
                acc[mt] = MFMA32(a[mt], b, acc[mt]);
            __builtin_amdgcn_s_setprio(0);
        }

        // ---- column-max reduce + atomics (relu folded into 0-init) ----
        float mx = 0.f;
        #pragma unroll
        for (int mt = 0; mt < 4; ++mt)
            #pragma unroll
            for (int e = 0; e < 16; ++e) mx = fmaxf(mx, acc[mt][e]);
        mx = fmaxf(mx, __shfl_xor(mx, 32, 64));
        if (hi == 0)
            atomicMax(&gout[cg * 256 + w * 32 + l31], __float_as_int(mx));
    }
}

// ---------------------------------------------------------------------------
// k4: classifier head, pure f32. One wave per output row.
// ---------------------------------------------------------------------------
__global__ void k4_f1(const float* __restrict__ wf1)
{
    int r = blockIdx.x, l = threadIdx.x;
    float s = 0.f;
    #pragma unroll
    for (int i = 0; i < 16; ++i) s += wf1[r * 1024 + i * 64 + l] * g_buf[i * 64 + l];
    #pragma unroll
    for (int o = 32; o; o >>= 1) s += __shfl_down(s, o, 64);
    if (!l) f1_buf[r] = fmaxf(s, 0.f);
}
__global__ void k4_f2(const float* __restrict__ wf2)
{
    int r = blockIdx.x, l = threadIdx.x;
    float s = 0.f;
    #pragma unroll
    for (int i = 0; i < 8; ++i) s += wf2[r * 512 + i * 64 + l] * f1_buf[i * 64 + l];
    #pragma unroll
    for (int o = 32; o; o >>= 1) s += __shfl_down(s, o, 64);
    if (!l) f2_buf[r] = fmaxf(s, 0.f);
}
__global__ void k4_out(const float* __restrict__ wf3, float* __restrict__ out)
{
    int r = blockIdx.x, l = threadIdx.x;
    float s = 0.f;
    #pragma unroll
    for (int i = 0; i < 4; ++i) s += wf3[r * 256 + i * 64 + l] * f2_buf[i * 64 + l];
    #pragma unroll
    for (int o = 32; o; o >>= 1) s += __shfl_down(s, o, 64);
    if (!l) out[r] = s;
}

// ---------------------------------------------------------------------------
extern "C" void kernel_launch(void* const* d_in, const int* in_sizes, int n_in,
                              void* d_out, int out_size, void* d_ws, size_t ws_size,
                              hipStream_t stream)
{
    (void)in_sizes; (void)n_in; (void)out_size; (void)d_ws; (void)ws_size;
    const float* x   = (const float*)d_in[0];
    const int*   idx = (const int*)d_in[2];
    const float* w1  = (const float*)d_in[3];
    const float* w2  = (const float*)d_in[4];
    const float* w3  = (const float*)d_in[5];
    const float* w4  = (const float*)d_in[6];
    const float* w5  = (const float*)d_in[7];
    const float* wf1 = (const float*)d_in[8];
    const float* wf2 = (const float*)d_in[9];
    const float* wf3 = (const float*)d_in[10];

    float* gptr;
    hipGetSymbolAddress((void**)&gptr, HIP_SYMBOL(g_buf));

    k0_zero <<<1, 1024, 0, stream>>>();
    kcvt    <<<833, 256, 0, stream>>>(w1, w2, w3, w4, w5);
    k1_mlp  <<<262144 / 64, 256, 0, stream>>>(x);
    k2_pool <<<262144 * 8 / 256, 256, 0, stream>>>(idx);
    k3_fused<<<2048, 512, 0, stream>>>((int*)gptr);
    k4_f1   <<<512, 64, 0, stream>>>(wf1);
    k4_f2   <<<256, 64, 0, stream>>>(wf2);
    k4_out  <<<40, 64, 0, stream>>>(wf3, (float*)d_out);
}